// Round 2
// baseline (407.391 us; speedup 1.0000x reference)
//
#include <hip/hip_runtime.h>
#include <stdint.h>

#define D_INC 512
#define D_HC  512
#define D_OC  128
#define N_EXPC 16

typedef __bf16 bf16x8 __attribute__((ext_vector_type(8)));
typedef float f32x4 __attribute__((ext_vector_type(4)));
typedef unsigned int u32x4 __attribute__((ext_vector_type(4)));
typedef unsigned short u16x8 __attribute__((ext_vector_type(8)));

__device__ __forceinline__ unsigned short f2bf(float f) {
    __bf16 b = (__bf16)f;                       // RNE convert on gfx950
    return __builtin_bit_cast(unsigned short, b);
}

__device__ __forceinline__ f32x4 mfma_bf16(bf16x8 a, bf16x8 b, f32x4 c) {
    return __builtin_amdgcn_mfma_f32_16x16x32_bf16(a, b, c, 0, 0, 0);
}

// ---------------------------------------------------------------------------
// K0: transpose + f32->bf16 convert.  src [R][C] f32  ->  dst [C][R] bf16
// batched over blockIdx.z with element strides sstride/dstride.
// ---------------------------------------------------------------------------
__global__ __launch_bounds__(256) void k_transpose_bf16(
    const float* __restrict__ src, unsigned short* __restrict__ dst,
    int R, int C, long sstride, long dstride)
{
    __shared__ unsigned short tile[64][72];     // +8 pad breaks bank pattern
    src += (size_t)blockIdx.z * sstride;
    dst += (size_t)blockIdx.z * dstride;
    int r0 = blockIdx.x * 64, c0 = blockIdx.y * 64;
    int t = threadIdx.x;
    {
        int r = t >> 2, cc = (t & 3) * 16;
        const float4* p = (const float4*)(src + (size_t)(r0 + r) * C + c0 + cc);
        #pragma unroll
        for (int i = 0; i < 4; i++) {
            float4 v = p[i];
            tile[r][cc + i * 4 + 0] = f2bf(v.x);
            tile[r][cc + i * 4 + 1] = f2bf(v.y);
            tile[r][cc + i * 4 + 2] = f2bf(v.z);
            tile[r][cc + i * 4 + 3] = f2bf(v.w);
        }
    }
    __syncthreads();
    {
        int c = t >> 2, rr = (t & 3) * 16;
        unsigned short buf[16];
        #pragma unroll
        for (int i = 0; i < 16; i++) buf[i] = tile[rr + i][c];
        u16x8* q = (u16x8*)(dst + (size_t)(c0 + c) * R + r0 + rr);
        q[0] = *(u16x8*)&buf[0];
        q[1] = *(u16x8*)&buf[8];
    }
}

// ---------------------------------------------------------------------------
// K1: h = relu(x @ W1 + b1), bf16 MFMA, 128x128 tile, BK=32, double-buffered.
// x f32 converted to bf16 during staging. W1t is [N][K] bf16 (pre-transposed).
// h stored bf16 [B][512].
// ---------------------------------------------------------------------------
__global__ __launch_bounds__(256, 2) void k_gemm1(
    const float* __restrict__ x, const unsigned short* __restrict__ w1t,
    const float* __restrict__ b1, unsigned short* __restrict__ h)
{
    __shared__ unsigned short lsA[2][128 * 32];
    __shared__ unsigned short lsB[2][128 * 32];

    int bid = blockIdx.x;                       // 2048 blocks, 2048 % 8 == 0
    int logical = (bid & 7) * 256 + (bid >> 3); // XCD-chunked swizzle
    int rb = logical >> 2, cb = logical & 3;
    long bm = (long)rb * 128;
    int bn = cb * 128;

    int t = threadIdx.x;
    int l = t & 63;
    int wid = t >> 6;
    int wr = (wid >> 1) * 64, wc = (wid & 1) * 64;
    int lr = l & 15, kc = (l >> 4) * 8;
    int srow = t >> 1, sc = (t & 1) * 16;

    f32x4 acc[4][4];
    #pragma unroll
    for (int i = 0; i < 4; i++)
        #pragma unroll
        for (int j = 0; j < 4; j++) acc[i][j] = (f32x4){0.f, 0.f, 0.f, 0.f};

    auto stage = [&](int buf, int k0) {
        // A: 128x32 from x (f32 -> bf16). thread: row=t>>1, 16 elems.
        const float4* xp = (const float4*)(x + (bm + srow) * D_INC + k0 + sc);
        float4 v0 = xp[0], v1 = xp[1], v2 = xp[2], v3 = xp[3];
        u16x8 p0, p1;
        p0[0] = f2bf(v0.x); p0[1] = f2bf(v0.y); p0[2] = f2bf(v0.z); p0[3] = f2bf(v0.w);
        p0[4] = f2bf(v1.x); p0[5] = f2bf(v1.y); p0[6] = f2bf(v1.z); p0[7] = f2bf(v1.w);
        p1[0] = f2bf(v2.x); p1[1] = f2bf(v2.y); p1[2] = f2bf(v2.z); p1[3] = f2bf(v2.w);
        p1[4] = f2bf(v3.x); p1[5] = f2bf(v3.y); p1[6] = f2bf(v3.z); p1[7] = f2bf(v3.w);
        *(u16x8*)&lsA[buf][srow * 32 + sc] = p0;
        *(u16x8*)&lsA[buf][srow * 32 + sc + 8] = p1;
        // B: 128x32 from w1t bf16 (straight copy)
        const u32x4* bp = (const u32x4*)(w1t + (size_t)(bn + srow) * D_INC + k0 + sc);
        u32x4 q0 = bp[0], q1 = bp[1];
        *(u32x4*)&lsB[buf][srow * 32 + sc] = q0;
        *(u32x4*)&lsB[buf][srow * 32 + sc + 8] = q1;
    };

    stage(0, 0);
    __syncthreads();
    #pragma unroll 2
    for (int ks = 0; ks < 16; ks++) {
        int cur = ks & 1;
        if (ks < 15) stage(cur ^ 1, (ks + 1) * 32);
        bf16x8 af[4], bfr[4];
        #pragma unroll
        for (int i = 0; i < 4; i++) {
            af[i]  = __builtin_bit_cast(bf16x8, *(const u32x4*)&lsA[cur][(wr + i * 16 + lr) * 32 + kc]);
            bfr[i] = __builtin_bit_cast(bf16x8, *(const u32x4*)&lsB[cur][(wc + i * 16 + lr) * 32 + kc]);
        }
        #pragma unroll
        for (int i = 0; i < 4; i++)
            #pragma unroll
            for (int j = 0; j < 4; j++)
                acc[i][j] = mfma_bf16(af[i], bfr[j], acc[i][j]);
        __syncthreads();
    }

    // epilogue: relu(acc + b1) -> h bf16.  D layout: col=lane&15, row=(l>>4)*4+r
    #pragma unroll
    for (int j = 0; j < 4; j++) {
        int col = bn + wc + j * 16 + lr;
        float bv = b1[col];
        #pragma unroll
        for (int i = 0; i < 4; i++) {
            long row = bm + wr + i * 16 + (l >> 4) * 4;
            #pragma unroll
            for (int r = 0; r < 4; r++) {
                float v = acc[i][j][r] + bv;
                v = fmaxf(v, 0.f);
                h[(row + r) * D_HC + col] = f2bf(v);
            }
        }
    }
}

// ---------------------------------------------------------------------------
// K2: routed head. Per block: 128 rows, build per-expert row lists (LDS
// atomics), pack same-expert rows into 16-row MFMA fragments, K-loop over 512
// with Wet[e] 128x32 tile double-buffered in LDS. gridDim.y=4 partitions the
// expert loop (e in {y, y+4, y+8, y+12}) for occupancy.
// ---------------------------------------------------------------------------
__global__ __launch_bounds__(256, 2) void k_gemm2(
    const unsigned short* __restrict__ h, const unsigned short* __restrict__ wet,
    const float* __restrict__ be, const int* __restrict__ num,
    const int* __restrict__ c, float* __restrict__ out)
{
    __shared__ unsigned short lsB[2][128 * 32];
    __shared__ unsigned char lst[N_EXPC][128];
    __shared__ int cnt[N_EXPC];

    long bm = (long)blockIdx.x * 128;
    int eq = blockIdx.y;                        // 0..3
    int t = threadIdx.x;
    int l = t & 63, w = t >> 6;
    int lr = l & 15, kc = (l >> 4) * 8;
    int srow = t >> 1, sc = (t & 1) * 16;

    if (t < N_EXPC) cnt[t] = 0;
    __syncthreads();
    if (t < 128) {
        int e = c[num[bm + t]];
        int slot = atomicAdd(&cnt[e], 1);
        lst[e][slot] = (unsigned char)t;
    }
    __syncthreads();

    for (int ei = 0; ei < 4; ei++) {
        int e = eq + ei * 4;
        int ce = cnt[e];
        if (ce == 0) continue;                  // uniform across block
        int ngrp = (ce + 15) >> 4;              // 1..8

        int rowid[8];
        #pragma unroll
        for (int g = 0; g < 8; g++) {
            int idx = g * 16 + lr;
            rowid[g] = lst[e][idx < ce ? idx : (ce - 1)];
        }

        f32x4 acc[8][2];
        #pragma unroll
        for (int g = 0; g < 8; g++) {
            acc[g][0] = (f32x4){0.f, 0.f, 0.f, 0.f};
            acc[g][1] = (f32x4){0.f, 0.f, 0.f, 0.f};
        }

        const unsigned short* wbase = wet + (size_t)e * D_OC * D_HC;
        auto stageB = [&](int buf, int k0) {
            const u32x4* bp = (const u32x4*)(wbase + (size_t)srow * D_HC + k0 + sc);
            u32x4 q0 = bp[0], q1 = bp[1];
            *(u32x4*)&lsB[buf][srow * 32 + sc] = q0;
            *(u32x4*)&lsB[buf][srow * 32 + sc + 8] = q1;
        };

        stageB(0, 0);
        __syncthreads();
        #pragma unroll 2
        for (int ks = 0; ks < 16; ks++) {
            int cur = ks & 1;
            if (ks < 15) stageB(cur ^ 1, (ks + 1) * 32);
            bf16x8 bf0 = __builtin_bit_cast(bf16x8, *(const u32x4*)&lsB[cur][(w * 32 + lr) * 32 + kc]);
            bf16x8 bf1 = __builtin_bit_cast(bf16x8, *(const u32x4*)&lsB[cur][(w * 32 + 16 + lr) * 32 + kc]);
            #pragma unroll
            for (int g = 0; g < 8; g++) {
                if (g < ngrp) {
                    bf16x8 af = __builtin_bit_cast(bf16x8,
                        *(const u32x4*)(h + (bm + rowid[g]) * D_HC + ks * 32 + kc));
                    acc[g][0] = mfma_bf16(af, bf0, acc[g][0]);
                    acc[g][1] = mfma_bf16(af, bf1, acc[g][1]);
                }
            }
            __syncthreads();
        }

        #pragma unroll
        for (int g = 0; g < 8; g++) {
            if (g >= ngrp) continue;
            #pragma unroll
            for (int fi = 0; fi < 2; fi++) {
                int col = w * 32 + fi * 16 + lr;
                float bev = be[e * D_OC + col];
                #pragma unroll
                for (int r = 0; r < 4; r++) {
                    int slot = g * 16 + (l >> 4) * 4 + r;
                    if (slot < ce) {
                        int row = lst[e][slot];
                        float v = acc[g][fi][r] + bev;
                        out[(bm + row) * D_OC + col] = 1.f / (1.f + __expf(-v));
                    }
                }
            }
        }
    }
}

// ---------------------------------------------------------------------------
extern "C" void kernel_launch(void* const* d_in, const int* in_sizes, int n_in,
                              void* d_out, int out_size, void* d_ws, size_t ws_size,
                              hipStream_t stream)
{
    const float* x  = (const float*)d_in[0];
    const int* num  = (const int*)d_in[1];
    const int* c    = (const int*)d_in[2];
    const float* W1 = (const float*)d_in[3];
    const float* b1 = (const float*)d_in[4];
    const float* We = (const float*)d_in[5];
    const float* be = (const float*)d_in[6];
    float* out = (float*)d_out;

    // workspace layout (ushort elements): W1t | Wet | h   (~67 MB total)
    unsigned short* w1t = (unsigned short*)d_ws;            // 512*512
    unsigned short* wet = w1t + 512 * 512;                  // 16*128*512
    unsigned short* hbuf = wet + 16 * 128 * 512;            // 65536*512

    dim3 b256(256);
    // W1 [512][512] -> W1t [512][512]
    k_transpose_bf16<<<dim3(8, 8, 1), b256, 0, stream>>>(W1, w1t, 512, 512, 0, 0);
    // We [16][512][128] -> Wet [16][128][512]
    k_transpose_bf16<<<dim3(8, 2, 16), b256, 0, stream>>>(We, wet, 512, 128,
                                                          (long)512 * 128, (long)512 * 128);
    k_gemm1<<<dim3(2048), b256, 0, stream>>>(x, w1t, b1, hbuf);
    k_gemm2<<<dim3(512, 4), b256, 0, stream>>>(hbuf, wet, be, num, c, out);
}

// Round 4
// 325.388 us; speedup vs baseline: 1.2520x; 1.2520x over previous
//
#include <hip/hip_runtime.h>
#include <stdint.h>

#define D_INC 512
#define D_HC  512
#define D_OC  128
#define N_EXPC 16
#define BROWS 65536
#define MAXTILES 528            // 16 experts * ceil + 65536/128

typedef __bf16 bf16x8 __attribute__((ext_vector_type(8)));
typedef float f32x4 __attribute__((ext_vector_type(4)));
typedef unsigned int u32x4 __attribute__((ext_vector_type(4)));
typedef unsigned short u16x8 __attribute__((ext_vector_type(8)));

__device__ __forceinline__ unsigned short f2bf(float f) {
    __bf16 b = (__bf16)f;
    return __builtin_bit_cast(unsigned short, b);
}

__device__ __forceinline__ f32x4 mfma_bf16(bf16x8 a, bf16x8 b, f32x4 c) {
    return __builtin_amdgcn_mfma_f32_16x16x32_bf16(a, b, c, 0, 0, 0);
}

// async global->LDS, 16B per lane. LDS dest is wave-uniform base + lane*16.
// Global source address is per-lane.
__device__ __forceinline__ void gl16(const unsigned short* g, unsigned short* l) {
    __builtin_amdgcn_global_load_lds(
        (const __attribute__((address_space(1))) void*)g,
        (__attribute__((address_space(3))) void*)l, 16, 0, 0);
}

// ---------------------------------------------------------------------------
// K0: transpose + f32->bf16.  src [R][C] f32 -> dst [C][R] bf16 (batched .z)
// ---------------------------------------------------------------------------
__global__ __launch_bounds__(256) void k_transpose_bf16(
    const float* __restrict__ src, unsigned short* __restrict__ dst,
    int R, int C, long sstride, long dstride)
{
    __shared__ unsigned short tile[64][72];
    src += (size_t)blockIdx.z * sstride;
    dst += (size_t)blockIdx.z * dstride;
    int r0 = blockIdx.x * 64, c0 = blockIdx.y * 64;
    int t = threadIdx.x;
    {
        int r = t >> 2, cc = (t & 3) * 16;
        const float4* p = (const float4*)(src + (size_t)(r0 + r) * C + c0 + cc);
        #pragma unroll
        for (int i = 0; i < 4; i++) {
            float4 v = p[i];
            tile[r][cc + i * 4 + 0] = f2bf(v.x);
            tile[r][cc + i * 4 + 1] = f2bf(v.y);
            tile[r][cc + i * 4 + 2] = f2bf(v.z);
            tile[r][cc + i * 4 + 3] = f2bf(v.w);
        }
    }
    __syncthreads();
    {
        int c = t >> 2, rr = (t & 3) * 16;
        unsigned short buf[16];
        #pragma unroll
        for (int i = 0; i < 16; i++) buf[i] = tile[rr + i][c];
        u16x8* q = (u16x8*)(dst + (size_t)(c0 + c) * R + r0 + rr);
        q[0] = *(u16x8*)&buf[0];
        q[1] = *(u16x8*)&buf[8];
    }
}

// ---------------------------------------------------------------------------
// Bucketing: e[i] = c[num[i]]; per-expert counts -> offsets -> scatter idx
// ---------------------------------------------------------------------------
__global__ __launch_bounds__(256) void k_hist(
    const int* __restrict__ num, const int* __restrict__ c, int* __restrict__ cnt)
{
    __shared__ int lh[N_EXPC];
    int t = threadIdx.x;
    if (t < N_EXPC) lh[t] = 0;
    __syncthreads();
    for (int i = blockIdx.x * 256 + t; i < BROWS; i += gridDim.x * 256)
        atomicAdd(&lh[c[num[i]]], 1);
    __syncthreads();
    if (t < N_EXPC) atomicAdd(&cnt[t], lh[t]);
}

// one block, 64 threads. base[e] = exclusive prefix; tbl[j] = {e, start, n}
__global__ __launch_bounds__(64) void k_scan(
    const int* __restrict__ cnt, int* __restrict__ base, int* __restrict__ tbl)
{
    __shared__ int sc[N_EXPC];
    int t = threadIdx.x;
    for (int j = t; j < MAXTILES; j += 64) tbl[j * 3 + 2] = 0;
    if (t < N_EXPC) sc[t] = cnt[t];
    __syncthreads();
    if (t < N_EXPC) {
        int run = 0, trun = 0;
        for (int e = 0; e < t; e++) { run += sc[e]; trun += (sc[e] + 127) >> 7; }
        base[t] = run;
        int ce = sc[t];
        for (int k = 0, j = trun; k < ce; k += 128, j++) {
            tbl[j * 3 + 0] = t;
            tbl[j * 3 + 1] = run + k;
            tbl[j * 3 + 2] = (ce - k < 128) ? (ce - k) : 128;
        }
    }
}

__global__ __launch_bounds__(256) void k_scatter(
    const int* __restrict__ num, const int* __restrict__ c,
    int* __restrict__ base, int* __restrict__ idx)
{
    __shared__ int lh[N_EXPC], lbase[N_EXPC];
    int t = threadIdx.x;
    if (t < N_EXPC) lh[t] = 0;
    __syncthreads();
    int i = blockIdx.x * 256 + t;               // grid == 256 blocks exactly
    int e = c[num[i]];
    int lo = atomicAdd(&lh[e], 1);
    __syncthreads();
    if (t < N_EXPC) lbase[t] = atomicAdd(&base[t], lh[t]);
    __syncthreads();
    idx[lbase[e] + lo] = i;
}

// ---------------------------------------------------------------------------
// K1: h = relu(x @ W1 + b1). 128x128 tile, BK=32, m97-style 2-barrier loop.
// A (x f32) reg-staged with cvt; B (w1t bf16) via global_load_lds width=16.
// ---------------------------------------------------------------------------
__global__ __launch_bounds__(256, 2) void k_gemm1(
    const float* __restrict__ x, const unsigned short* __restrict__ w1t,
    const float* __restrict__ b1, unsigned short* __restrict__ h)
{
    __shared__ unsigned short lsA[128 * 32];
    __shared__ unsigned short lsB[128 * 32];

    int bid = blockIdx.x;                       // 2048 % 8 == 0 -> bijective
    int logical = (bid & 7) * 256 + (bid >> 3); // XCD-chunked swizzle
    int rb = logical >> 2, cb = logical & 3;
    long bm = (long)rb * 128;
    int bn = cb * 128;

    int t = threadIdx.x;
    int l = t & 63, wid = t >> 6;
    int wr = (wid >> 1) * 64, wc = (wid & 1) * 64;
    int lr = l & 15, kc = (l >> 4) * 8;
    int srow = t >> 1, sc = (t & 1) * 16;

    // B staging sources: wave wid covers rows [wid*32, wid*32+32), 2 insts
    const unsigned short* bsrc0 =
        w1t + (size_t)(bn + wid * 32 + (l >> 2)) * D_INC + (l & 3) * 8;
    const unsigned short* bsrc1 = bsrc0 + (size_t)16 * D_INC;
    unsigned short* bdst0 = &lsB[(wid * 32) * 32];
    unsigned short* bdst1 = &lsB[(wid * 32 + 16) * 32];
    const float* xrow = x + (bm + srow) * D_INC + sc;

    f32x4 acc[4][4];
    #pragma unroll
    for (int i = 0; i < 4; i++)
        #pragma unroll
        for (int j = 0; j < 4; j++) acc[i][j] = (f32x4){0.f, 0.f, 0.f, 0.f};

    auto stage = [&](int k0) {
        const float4* xp = (const float4*)(xrow + k0);
        float4 v0 = xp[0], v1 = xp[1], v2 = xp[2], v3 = xp[3];
        u16x8 p0, p1;
        p0[0] = f2bf(v0.x); p0[1] = f2bf(v0.y); p0[2] = f2bf(v0.z); p0[3] = f2bf(v0.w);
        p0[4] = f2bf(v1.x); p0[5] = f2bf(v1.y); p0[6] = f2bf(v1.z); p0[7] = f2bf(v1.w);
        p1[0] = f2bf(v2.x); p1[1] = f2bf(v2.y); p1[2] = f2bf(v2.z); p1[3] = f2bf(v2.w);
        p1[4] = f2bf(v3.x); p1[5] = f2bf(v3.y); p1[6] = f2bf(v3.z); p1[7] = f2bf(v3.w);
        *(u16x8*)&lsA[srow * 32 + sc] = p0;
        *(u16x8*)&lsA[srow * 32 + sc + 8] = p1;
        gl16(bsrc0 + k0, bdst0);
        gl16(bsrc1 + k0, bdst1);
    };

    stage(0);
    #pragma unroll 4
    for (int ks = 0; ks < 16; ks++) {
        __syncthreads();                        // staging landed (vmcnt drained)
        bf16x8 af[4], bfr[4];
        #pragma unroll
        for (int i = 0; i < 4; i++) {
            af[i]  = __builtin_bit_cast(bf16x8, *(const u32x4*)&lsA[(wr + i * 16 + lr) * 32 + kc]);
            bfr[i] = __builtin_bit_cast(bf16x8, *(const u32x4*)&lsB[(wc + i * 16 + lr) * 32 + kc]);
        }
        #pragma unroll
        for (int i = 0; i < 4; i++)
            #pragma unroll
            for (int j = 0; j < 4; j++)
                acc[i][j] = mfma_bf16(af[i], bfr[j], acc[i][j]);
        if (ks < 15) {
            __syncthreads();                    // frag reads done, LDS reusable
            stage((ks + 1) * 32);
        }
    }

    #pragma unroll
    for (int j = 0; j < 4; j++) {
        int col = bn + wc + j * 16 + lr;
        float bv = b1[col];
        #pragma unroll
        for (int i = 0; i < 4; i++) {
            long row = bm + wr + i * 16 + (l >> 4) * 4;
            #pragma unroll
            for (int r = 0; r < 4; r++) {
                float v = fmaxf(acc[i][j][r] + bv, 0.f);
                h[(row + r) * D_HC + col] = f2bf(v);
            }
        }
    }
}

// ---------------------------------------------------------------------------
// K2g: grouped routed head. Block j: tbl[j] = {e, start, n} -> 128 gathered
// same-expert rows x 128 cols, K=512. A gathered from h via global_load_lds
// (per-lane global addr, linear LDS). B = Wet[e] tile via global_load_lds.
// ---------------------------------------------------------------------------
__global__ __launch_bounds__(256, 2) void k_gemm2g(
    const unsigned short* __restrict__ h, const unsigned short* __restrict__ wet,
    const float* __restrict__ be, const int* __restrict__ idx,
    const int* __restrict__ tbl, float* __restrict__ out)
{
    __shared__ unsigned short lsA[128 * 32];
    __shared__ unsigned short lsB[128 * 32];
    __shared__ int rowid[128];

    int bj = blockIdx.x;
    int e = tbl[bj * 3 + 0], s = tbl[bj * 3 + 1], n = tbl[bj * 3 + 2];
    if (n == 0) return;

    int t = threadIdx.x;
    int l = t & 63, wid = t >> 6;
    int wr = (wid >> 1) * 64, wc = (wid & 1) * 64;
    int lr = l & 15, kc = (l >> 4) * 8;

    if (t < 128) rowid[t] = idx[s + (t < n ? t : n - 1)];
    __syncthreads();

    int ar0 = wid * 32 + (l >> 2);
    const unsigned short* asrc0 = h + (size_t)rowid[ar0] * D_HC + (l & 3) * 8;
    const unsigned short* asrc1 = h + (size_t)rowid[ar0 + 16] * D_HC + (l & 3) * 8;
    const unsigned short* wbase = wet + (size_t)e * D_OC * D_HC;
    const unsigned short* bsrc0 =
        wbase + (size_t)(wid * 32 + (l >> 2)) * D_HC + (l & 3) * 8;
    const unsigned short* bsrc1 = bsrc0 + (size_t)16 * D_HC;
    unsigned short* adst0 = &lsA[(wid * 32) * 32];
    unsigned short* adst1 = &lsA[(wid * 32 + 16) * 32];
    unsigned short* bdst0 = &lsB[(wid * 32) * 32];
    unsigned short* bdst1 = &lsB[(wid * 32 + 16) * 32];

    f32x4 acc[4][4];
    #pragma unroll
    for (int i = 0; i < 4; i++)
        #pragma unroll
        for (int j = 0; j < 4; j++) acc[i][j] = (f32x4){0.f, 0.f, 0.f, 0.f};

    auto stage = [&](int k0) {
        gl16(asrc0 + k0, adst0);
        gl16(asrc1 + k0, adst1);
        gl16(bsrc0 + k0, bdst0);
        gl16(bsrc1 + k0, bdst1);
    };

    stage(0);
    #pragma unroll 4
    for (int ks = 0; ks < 16; ks++) {
        __syncthreads();
        bf16x8 af[4], bfr[4];
        #pragma unroll
        for (int i = 0; i < 4; i++) {
            af[i]  = __builtin_bit_cast(bf16x8, *(const u32x4*)&lsA[(wr + i * 16 + lr) * 32 + kc]);
            bfr[i] = __builtin_bit_cast(bf16x8, *(const u32x4*)&lsB[(wc + i * 16 + lr) * 32 + kc]);
        }
        #pragma unroll
        for (int i = 0; i < 4; i++)
            #pragma unroll
            for (int j = 0; j < 4; j++)
                acc[i][j] = mfma_bf16(af[i], bfr[j], acc[i][j]);
        if (ks < 15) {
            __syncthreads();
            stage((ks + 1) * 32);
        }
    }

    #pragma unroll
    for (int j = 0; j < 4; j++) {
        int col = wc + j * 16 + lr;
        float bev = be[e * D_OC + col];
        #pragma unroll
        for (int i = 0; i < 4; i++) {
            int rl = wr + i * 16 + (l >> 4) * 4;
            #pragma unroll
            for (int r = 0; r < 4; r++) {
                if (rl + r < n) {
                    float v = acc[i][j][r] + bev;
                    out[(size_t)rowid[rl + r] * D_OC + col] = 1.f / (1.f + __expf(-v));
                }
            }
        }
    }
}

// ---------------------------------------------------------------------------
extern "C" void kernel_launch(void* const* d_in, const int* in_sizes, int n_in,
                              void* d_out, int out_size, void* d_ws, size_t ws_size,
                              hipStream_t stream)
{
    const float* x  = (const float*)d_in[0];
    const int* num  = (const int*)d_in[1];
    const int* c    = (const int*)d_in[2];
    const float* W1 = (const float*)d_in[3];
    const float* b1 = (const float*)d_in[4];
    const float* We = (const float*)d_in[5];
    const float* be = (const float*)d_in[6];
    float* out = (float*)d_out;

    uint8_t* p = (uint8_t*)d_ws;
    unsigned short* w1t  = (unsigned short*)p;  p += (size_t)512 * 512 * 2;
    unsigned short* wet  = (unsigned short*)p;  p += (size_t)16 * 128 * 512 * 2;
    unsigned short* hbuf = (unsigned short*)p;  p += (size_t)BROWS * 512 * 2;
    int* cnt  = (int*)p;  p += N_EXPC * 4;
    int* base = (int*)p;  p += N_EXPC * 4;
    int* tbl  = (int*)p;  p += MAXTILES * 3 * 4;
    int* idx  = (int*)p;  p += (size_t)BROWS * 4;

    dim3 b256(256);
    hipMemsetAsync(cnt, 0, N_EXPC * sizeof(int), stream);
    k_hist<<<dim3(256), b256, 0, stream>>>(num, c, cnt);
    k_scan<<<dim3(1), dim3(64), 0, stream>>>(cnt, base, tbl);
    k_scatter<<<dim3(256), b256, 0, stream>>>(num, c, base, idx);
    k_transpose_bf16<<<dim3(8, 8, 1), b256, 0, stream>>>(W1, w1t, 512, 512, 0, 0);
    k_transpose_bf16<<<dim3(8, 2, 16), b256, 0, stream>>>(We, wet, 512, 128,
                                                          (long)512 * 128, (long)512 * 128);
    k_gemm1<<<dim3(2048), b256, 0, stream>>>(x, w1t, b1, hbuf);
    k_gemm2g<<<dim3(MAXTILES), b256, 0, stream>>>(hbuf, wet, be, idx, tbl, out);
}